// Round 2
// baseline (669.370 us; speedup 1.0000x reference)
//
#include <hip/hip_runtime.h>
#include <stdint.h>

// Problem constants
#define BD   16
#define CD   512
#define HD_  64
#define NH_  8
#define HWD  4096
#define LD   77
#define DD   768

typedef __bf16 bf16;
typedef bf16 bf16x8 __attribute__((ext_vector_type(8)));
typedef float f32x4 __attribute__((ext_vector_type(4)));

__device__ __forceinline__ void async16(const bf16* g, bf16* l) {
  __builtin_amdgcn_global_load_lds(
      (const __attribute__((address_space(1))) void*)g,
      (__attribute__((address_space(3))) void*)l, 16, 0, 0);
}

__device__ __forceinline__ unsigned short bfb(float f) {
  bf16 h = (bf16)f;
  return __builtin_bit_cast(unsigned short, h);
}

// ---------------------------------------------------------------------------
// K0a: transpose+convert x [B,C,HW] f32 -> xt [B*HW, C] bf16 (LDS tile xpose)
// ---------------------------------------------------------------------------
__global__ __launch_bounds__(256) void xpose_cvt(const float* __restrict__ X,
                                                 bf16* __restrict__ Y) {
  __shared__ float tile[64][68];
  const int b = blockIdx.z, c0 = blockIdx.y * 64, t0 = blockIdx.x * 64;
  const int tid = threadIdx.x;
  const float* Xb = X + ((size_t)b * CD + c0) * HWD + t0;
#pragma unroll
  for (int p = 0; p < 4; ++p) {
    int c = (tid >> 4) + p * 16;
    int t = (tid & 15) * 4;
    float4 v = *(const float4*)(Xb + (size_t)c * HWD + t);
    *(float4*)&tile[c][t] = v;
  }
  __syncthreads();
  int t = tid >> 2, cb = (tid & 3) * 16;
  union { uint4 u[2]; unsigned short us[16]; } pk;
#pragma unroll
  for (int j = 0; j < 16; ++j) pk.us[j] = bfb(tile[cb + j][t]);
  uint4* Yp = (uint4*)(Y + ((size_t)(b * HWD + t0 + t)) * CD + c0 + cb);
  Yp[0] = pk.u[0];
  Yp[1] = pk.u[1];
}

// ---------------------------------------------------------------------------
// K0b: generic f32 -> bf16 convert (n multiple of 8)
// ---------------------------------------------------------------------------
__global__ void cvt_bf16_k(const float* __restrict__ X, bf16* __restrict__ Y, int n) {
  int i = (blockIdx.x * 256 + threadIdx.x) * 8;
  if (i >= n) return;
  float4 a = *(const float4*)(X + i);
  float4 c = *(const float4*)(X + i + 4);
  union { uint4 u; unsigned short us[8]; } pk;
  pk.us[0] = bfb(a.x); pk.us[1] = bfb(a.y); pk.us[2] = bfb(a.z); pk.us[3] = bfb(a.w);
  pk.us[4] = bfb(c.x); pk.us[5] = bfb(c.y); pk.us[6] = bfb(c.z); pk.us[7] = bfb(c.w);
  *(uint4*)(Y + i) = pk.u;
}

// ---------------------------------------------------------------------------
// KV GEMM (m97 style): D[M,512] = A[M,K] * B[512,K]^T + bias, M row-guarded
// ---------------------------------------------------------------------------
__global__ __launch_bounds__(256)
void gemm_kv(const bf16* __restrict__ A, const bf16* __restrict__ B,
             int M, int K, const float* __restrict__ bias,
             float* __restrict__ D) {
  constexpr int TM = 128, TN = 128;
  constexpr int WM = 64, WN = 64, AFR = 4, BFR = 4;
  __shared__ bf16 sA[TM * 64];
  __shared__ bf16 sB[TN * 64];
  const int tid = threadIdx.x, wave = tid >> 6, lane = tid & 63;
  const int m0 = blockIdx.y * TM, n0 = blockIdx.x * TN;
  const int wm = (wave >> 1) * WM, wn = (wave & 1) * WN;
  const int sub = lane >> 3, col8 = (lane & 7) * 8;
  const int mlo = lane & 15, khi = lane >> 4;
  f32x4 acc[AFR][BFR] = {};

  for (int k0 = 0; k0 < K; k0 += 64) {
#pragma unroll
    for (int r = 0; r < 8; ++r) {
      int ci = wave * 8 + r;
      if (ci < 16) {
        int row = ci * 8 + sub;
        int g = m0 + row;
        if (g > M - 1) g = M - 1;
        async16(A + (size_t)g * K + k0 + col8, &sA[ci * 512]);
      } else {
        int cj = ci - 16;
        int row = cj * 8 + sub;
        async16(B + (size_t)(n0 + row) * K + k0 + col8, &sB[cj * 512]);
      }
    }
    __syncthreads();
#pragma unroll
    for (int kc = 0; kc < 2; ++kc) {
      bf16x8 af[AFR], bfv[BFR];
      const int ko = kc * 32 + khi * 8;
#pragma unroll
      for (int i = 0; i < AFR; ++i)
        af[i] = *(const bf16x8*)&sA[(wm + i * 16 + mlo) * 64 + ko];
#pragma unroll
      for (int j = 0; j < BFR; ++j)
        bfv[j] = *(const bf16x8*)&sB[(wn + j * 16 + mlo) * 64 + ko];
#pragma unroll
      for (int i = 0; i < AFR; ++i)
#pragma unroll
        for (int j = 0; j < BFR; ++j)
          acc[i][j] = __builtin_amdgcn_mfma_f32_16x16x32_bf16(af[i], bfv[j],
                                                              acc[i][j], 0, 0, 0);
    }
    __syncthreads();
  }

#pragma unroll
  for (int i = 0; i < AFR; ++i) {
    const int mb = m0 + wm + i * 16 + khi * 4;
#pragma unroll
    for (int j = 0; j < BFR; ++j) {
      const int n = n0 + wn + j * 16 + mlo;
#pragma unroll
      for (int r = 0; r < 4; ++r) {
        const int m = mb + r;
        if (m < M) D[(size_t)m * CD + n] = acc[i][j][r] + bias[n];
      }
    }
  }
}

// ---------------------------------------------------------------------------
// Q projection + bias + posenc + fused LayerNorm -> bf16 (in-place safe: each
// block writes only the rows it exclusively reads as A).
// TM=64 tokens/block, TN=512 (full channel dim), K=512.
// A staged via global_load_lds (8 KB); B (wq, 0.5 MB) read direct from L2.
// ---------------------------------------------------------------------------
__global__ __launch_bounds__(256)
void gemm_q_ln(const bf16* __restrict__ A, const bf16* __restrict__ B,
               const float* __restrict__ bq, const float* __restrict__ g1,
               const float* __restrict__ b1, bf16* __restrict__ Y) {
  __shared__ bf16 sA[64 * 64];
  __shared__ float sStat[64][8];  // [row][wave*2 + {sum,sumsq}]
  const int tid = threadIdx.x, wave = tid >> 6, lane = tid & 63;
  const int m0 = blockIdx.x * 64;
  const int wn = wave * 128;  // waves split N: WN=128
  const int mlo = lane & 15, khi = lane >> 4;
  const int sub = lane >> 3, col8 = (lane & 7) * 8;
  f32x4 acc[4][8] = {};

  for (int k0 = 0; k0 < CD; k0 += 64) {
    async16(A + (size_t)(m0 + wave * 8 + sub) * CD + k0 + col8,
            &sA[wave * 8 * 64]);
    async16(A + (size_t)(m0 + 32 + wave * 8 + sub) * CD + k0 + col8,
            &sA[(32 + wave * 8) * 64]);
    __syncthreads();
#pragma unroll
    for (int kc = 0; kc < 2; ++kc) {
      const int ko = kc * 32 + khi * 8;
      bf16x8 af[4];
#pragma unroll
      for (int i = 0; i < 4; ++i)
        af[i] = *(const bf16x8*)&sA[(i * 16 + mlo) * 64 + ko];
      const bf16* Bp = B + (size_t)(wn + mlo) * CD + k0 + ko;
#pragma unroll
      for (int j = 0; j < 8; ++j) {
        bf16x8 bv = *(const bf16x8*)(Bp + (size_t)j * 16 * CD);
#pragma unroll
        for (int i = 0; i < 4; ++i)
          acc[i][j] = __builtin_amdgcn_mfma_f32_16x16x32_bf16(af[i], bv,
                                                              acc[i][j], 0, 0, 0);
      }
    }
    __syncthreads();
  }

  // epilogue: +bq +posenc, then LN over the 512 channels of each row
  float bqf[8], g1f[8], b1f[8];
#pragma unroll
  for (int j = 0; j < 8; ++j) {
    int col = wn + j * 16 + mlo;
    bqf[j] = bq[col];
    g1f[j] = g1[col];
    b1f[j] = b1[col];
  }
  const float pescale = 0.05f / 63.0f;
#pragma unroll
  for (int i = 0; i < 4; ++i) {
#pragma unroll
    for (int r = 0; r < 4; ++r) {
      int rloc = i * 16 + khi * 4 + r;
      int hw = (m0 + rloc) & (HWD - 1);
      float pe = (float)((wn < 256) ? (hw & 63) : (hw >> 6)) * pescale;
      float s = 0.f, sq = 0.f;
#pragma unroll
      for (int j = 0; j < 8; ++j) {
        float v = acc[i][j][r] + bqf[j] + pe;
        acc[i][j][r] = v;
        s += v;
        sq += v * v;
      }
#pragma unroll
      for (int off = 1; off < 16; off <<= 1) {
        s += __shfl_xor(s, off);
        sq += __shfl_xor(sq, off);
      }
      if (mlo == 0) {
        sStat[rloc][wave * 2] = s;
        sStat[rloc][wave * 2 + 1] = sq;
      }
    }
  }
  __syncthreads();
#pragma unroll
  for (int i = 0; i < 4; ++i) {
#pragma unroll
    for (int r = 0; r < 4; ++r) {
      int rloc = i * 16 + khi * 4 + r;
      float s = sStat[rloc][0] + sStat[rloc][2] + sStat[rloc][4] + sStat[rloc][6];
      float sq = sStat[rloc][1] + sStat[rloc][3] + sStat[rloc][5] + sStat[rloc][7];
      float mean = s * (1.0f / 512.0f);
      float var = sq * (1.0f / 512.0f) - mean * mean;
      float rstd = rsqrtf(var + 1e-5f);
      bf16* yr = Y + (size_t)(m0 + rloc) * CD + wn + mlo;
#pragma unroll
      for (int j = 0; j < 8; ++j)
        yr[j * 16] = (bf16)((acc[i][j][r] - mean) * rstd * g1f[j] + b1f[j]);
    }
  }
}

// ---------------------------------------------------------------------------
// O projection, transposed output: out[b,c,hw] = Wo . attn_o^T + bo + x.
// TM=512 channels (A=Wo 0.5 MB, direct from L2), TN=64 tokens/block (LDS).
// ---------------------------------------------------------------------------
__global__ __launch_bounds__(256)
void gemm_o(const bf16* __restrict__ Wo, const bf16* __restrict__ AO,
            const float* __restrict__ bo, const float* __restrict__ xres,
            float* __restrict__ out) {
  __shared__ bf16 sB[64 * 64];
  const int tid = threadIdx.x, wave = tid >> 6, lane = tid & 63;
  const int n0 = blockIdx.x * 64;
  const int wm = wave * 128;  // waves split M: WM=128
  const int mlo = lane & 15, khi = lane >> 4;
  const int sub = lane >> 3, col8 = (lane & 7) * 8;
  f32x4 acc[8][4] = {};

  for (int k0 = 0; k0 < CD; k0 += 64) {
    async16(AO + (size_t)(n0 + wave * 8 + sub) * CD + k0 + col8,
            &sB[wave * 8 * 64]);
    async16(AO + (size_t)(n0 + 32 + wave * 8 + sub) * CD + k0 + col8,
            &sB[(32 + wave * 8) * 64]);
    __syncthreads();
#pragma unroll
    for (int kc = 0; kc < 2; ++kc) {
      const int ko = kc * 32 + khi * 8;
      bf16x8 bfv[4];
#pragma unroll
      for (int j = 0; j < 4; ++j)
        bfv[j] = *(const bf16x8*)&sB[(j * 16 + mlo) * 64 + ko];
      const bf16* Ap = Wo + (size_t)(wm + mlo) * CD + k0 + ko;
#pragma unroll
      for (int i = 0; i < 8; ++i) {
        bf16x8 av = *(const bf16x8*)(Ap + (size_t)i * 16 * CD);
#pragma unroll
        for (int j = 0; j < 4; ++j)
          acc[i][j] = __builtin_amdgcn_mfma_f32_16x16x32_bf16(av, bfv[j],
                                                              acc[i][j], 0, 0, 0);
      }
    }
    __syncthreads();
  }

#pragma unroll
  for (int i = 0; i < 8; ++i) {
#pragma unroll
    for (int r = 0; r < 4; ++r) {
      const int m = wm + i * 16 + khi * 4 + r;  // channel
      const float bom = bo[m];
#pragma unroll
      for (int j = 0; j < 4; ++j) {
        const int n = n0 + j * 16 + mlo;  // token
        const int b = n >> 12, hw = n & (HWD - 1);
        size_t addr = ((size_t)(b * CD + m)) * HWD + hw;
        out[addr] = acc[i][j][r] + bom + xres[addr];
      }
    }
  }
}

// ---------------------------------------------------------------------------
// LayerNorm over rows of 512 (wave per row) -> kh [B,NH,L,HD] bf16 head-split
// ---------------------------------------------------------------------------
__global__ __launch_bounds__(256) void ln_rows_k(const float* __restrict__ X,
                                                 const float* __restrict__ gg,
                                                 const float* __restrict__ bb,
                                                 bf16* __restrict__ Y, int nrows) {
  const int wv = threadIdx.x >> 6, lane = threadIdx.x & 63;
  const int row = blockIdx.x * 4 + wv;
  if (row >= nrows) return;
  const float* xr = X + (size_t)row * CD + lane * 8;
  float4 v0 = *(const float4*)xr;
  float4 v1 = *(const float4*)(xr + 4);
  float xv[8] = {v0.x, v0.y, v0.z, v0.w, v1.x, v1.y, v1.z, v1.w};
  float s = 0.f, sq = 0.f;
#pragma unroll
  for (int j = 0; j < 8; ++j) { s += xv[j]; sq += xv[j] * xv[j]; }
#pragma unroll
  for (int off = 1; off < 64; off <<= 1) {
    s += __shfl_xor(s, off);
    sq += __shfl_xor(sq, off);
  }
  float mean = s * (1.0f / 512.0f);
  float var = sq * (1.0f / 512.0f) - mean * mean;
  float rstd = rsqrtf(var + 1e-5f);
  const int c0 = lane * 8;
  union { uint4 u; unsigned short us[8]; } pk;
#pragma unroll
  for (int j = 0; j < 8; ++j)
    pk.us[j] = bfb((xv[j] - mean) * rstd * gg[c0 + j] + bb[c0 + j]);
  int bq = row / LD, l = row - bq * LD;
  int hh = lane >> 3, dd = (lane & 7) * 8;
  size_t ya = (((size_t)(bq * NH_ + hh)) * LD + l) * HD_ + dd;
  *(uint4*)(Y + ya) = pk.u;
}

// ---------------------------------------------------------------------------
// vraw [B*L, 512] fp32 -> vt [B*NH, HD, 96] bf16 (key dim transposed, padded)
// ---------------------------------------------------------------------------
__global__ __launch_bounds__(256) void make_vt(const float* __restrict__ vraw,
                                               bf16* __restrict__ vt) {
  const int bh = blockIdx.x, b = bh >> 3, h = bh & 7;
  const int tid = threadIdx.x, d = tid & 63, lg = tid >> 6;
  for (int l = lg; l < 96; l += 4) {
    float v = 0.f;
    if (l < LD) v = vraw[((size_t)(b * LD + l)) * CD + h * HD_ + d];
    vt[((size_t)(bh * HD_ + d)) * 96 + l] = (bf16)v;
  }
}

// ---------------------------------------------------------------------------
// Attention: block = (64 queries, head h, batch b); 4 waves x 16-query strips.
// ---------------------------------------------------------------------------
__global__ __launch_bounds__(256) void attn_k(const bf16* __restrict__ Q,
                                              const bf16* __restrict__ KH,
                                              const bf16* __restrict__ VT,
                                              bf16* __restrict__ O) {
  __shared__ bf16 P[4][16 * 104];
  const int tid = threadIdx.x, wv = tid >> 6, lane = tid & 63;
  const int m = lane & 15, kg = lane >> 4;
  const int q0 = blockIdx.x * 64, h = blockIdx.y, b = blockIdx.z;
  const int bh = b * NH_ + h;

  const size_t qoff = ((size_t)(b * HWD + q0 + wv * 16 + m)) * CD + h * HD_;
  bf16x8 a0 = *(const bf16x8*)(Q + qoff + kg * 8);
  bf16x8 a1 = *(const bf16x8*)(Q + qoff + 32 + kg * 8);

  const bf16* Kb = KH + (size_t)bh * LD * HD_;
  f32x4 s[5];
#pragma unroll
  for (int kt = 0; kt < 5; ++kt) {
    int key = kt * 16 + m;
    if (key > LD - 1) key = LD - 1;
    const bf16* kr = Kb + key * HD_ + kg * 8;
    bf16x8 b0 = *(const bf16x8*)kr;
    bf16x8 b1 = *(const bf16x8*)(kr + 32);
    f32x4 z = {0.f, 0.f, 0.f, 0.f};
    z = __builtin_amdgcn_mfma_f32_16x16x32_bf16(a0, b0, z, 0, 0, 0);
    z = __builtin_amdgcn_mfma_f32_16x16x32_bf16(a1, b1, z, 0, 0, 0);
    s[kt] = z;
  }

  bf16* Pw = &P[wv][0];
#pragma unroll
  for (int r = 0; r < 4; ++r) {
    float sc[5];
#pragma unroll
    for (int kt = 0; kt < 5; ++kt) {
      float v = s[kt][r] * 0.125f;
      if (kt == 4 && m >= LD - 64) v = -3.0e38f;
      sc[kt] = v;
    }
    float mx = fmaxf(fmaxf(fmaxf(sc[0], sc[1]), fmaxf(sc[2], sc[3])), sc[4]);
    mx = fmaxf(mx, __shfl_xor(mx, 1));
    mx = fmaxf(mx, __shfl_xor(mx, 2));
    mx = fmaxf(mx, __shfl_xor(mx, 4));
    mx = fmaxf(mx, __shfl_xor(mx, 8));
    float sum = 0.f;
#pragma unroll
    for (int kt = 0; kt < 5; ++kt) {
      sc[kt] = __expf(sc[kt] - mx);
      sum += sc[kt];
    }
    sum += __shfl_xor(sum, 1);
    sum += __shfl_xor(sum, 2);
    sum += __shfl_xor(sum, 4);
    sum += __shfl_xor(sum, 8);
    float inv = 1.0f / sum;
    const int prow = kg * 4 + r;
#pragma unroll
    for (int kt = 0; kt < 5; ++kt)
      Pw[prow * 104 + kt * 16 + m] = (bf16)(sc[kt] * inv);
    Pw[prow * 104 + 80 + m] = (bf16)0.f;
  }
  __syncthreads();

  bf16x8 ap[3];
#pragma unroll
  for (int kc = 0; kc < 3; ++kc)
    ap[kc] = *(const bf16x8*)&Pw[m * 104 + kc * 32 + kg * 8];

  const bf16* Vb = VT + (size_t)bh * HD_ * 96;
  f32x4 o[4] = {};
#pragma unroll
  for (int nt = 0; nt < 4; ++nt) {
#pragma unroll
    for (int kc = 0; kc < 3; ++kc) {
      bf16x8 bv = *(const bf16x8*)(Vb + (nt * 16 + m) * 96 + kc * 32 + kg * 8);
      o[nt] = __builtin_amdgcn_mfma_f32_16x16x32_bf16(ap[kc], bv, o[nt], 0, 0, 0);
    }
  }
#pragma unroll
  for (int nt = 0; nt < 4; ++nt)
#pragma unroll
    for (int r = 0; r < 4; ++r) {
      const int row = b * HWD + q0 + wv * 16 + kg * 4 + r;
      O[(size_t)row * CD + h * HD_ + nt * 16 + m] = (bf16)(o[nt][r]);
    }
}

// ---------------------------------------------------------------------------
extern "C" void kernel_launch(void* const* d_in, const int* in_sizes, int n_in,
                              void* d_out, int out_size, void* d_ws, size_t ws_size,
                              hipStream_t stream) {
  const float* x    = (const float*)d_in[0];
  const float* text = (const float*)d_in[1];
  const float* wq   = (const float*)d_in[2];
  const float* bq   = (const float*)d_in[3];
  const float* wk   = (const float*)d_in[4];
  const float* bk   = (const float*)d_in[5];
  const float* wv   = (const float*)d_in[6];
  const float* bv   = (const float*)d_in[7];
  const float* wo   = (const float*)d_in[8];
  const float* bo   = (const float*)d_in[9];
  const float* g1   = (const float*)d_in[10];
  const float* b1   = (const float*)d_in[11];
  const float* g2   = (const float*)d_in[12];
  const float* b2   = (const float*)d_in[13];
  float* out = (float*)d_out;

  char* p = (char*)d_ws;
  auto alloc = [&](size_t bytes) {
    char* r = p;
    p += (bytes + 255) & ~(size_t)255;
    return r;
  };
  bf16* xt     = (bf16*)alloc((size_t)BD * HWD * CD * 2);  // becomes qbf in-place
  bf16* attn_o = (bf16*)alloc((size_t)BD * HWD * CD * 2);
  bf16* textb  = (bf16*)alloc((size_t)BD * LD * DD * 2);
  bf16* wqb    = (bf16*)alloc((size_t)CD * CD * 2);
  bf16* wkb    = (bf16*)alloc((size_t)CD * DD * 2);
  bf16* wvb    = (bf16*)alloc((size_t)CD * DD * 2);
  bf16* wob    = (bf16*)alloc((size_t)CD * CD * 2);
  float* kraw  = (float*)alloc((size_t)BD * LD * CD * 4);
  float* vraw  = (float*)alloc((size_t)BD * LD * CD * 4);
  bf16* kh     = (bf16*)alloc((size_t)BD * NH_ * LD * HD_ * 2);
  bf16* vt     = (bf16*)alloc((size_t)BD * NH_ * HD_ * 96 * 2);
  bf16* qbf = xt;  // in-place: each gemm_q_ln block writes only its own rows

  // 0: convert inputs
  xpose_cvt<<<dim3(HWD / 64, CD / 64, BD), 256, 0, stream>>>(x, xt);
  const int nt_ = BD * LD * DD;
  cvt_bf16_k<<<(nt_ / 8 + 255) / 256, 256, 0, stream>>>(text, textb, nt_);
  cvt_bf16_k<<<(CD * CD / 8 + 255) / 256, 256, 0, stream>>>(wq, wqb, CD * CD);
  cvt_bf16_k<<<(CD * DD / 8 + 255) / 256, 256, 0, stream>>>(wk, wkb, CD * DD);
  cvt_bf16_k<<<(CD * DD / 8 + 255) / 256, 256, 0, stream>>>(wv, wvb, CD * DD);
  cvt_bf16_k<<<(CD * CD / 8 + 255) / 256, 256, 0, stream>>>(wo, wob, CD * CD);

  // 1: K/V projections, LN(k), V transpose
  gemm_kv<<<dim3(4, 10), 256, 0, stream>>>(textb, wkb, BD * LD, DD, bk, kraw);
  gemm_kv<<<dim3(4, 10), 256, 0, stream>>>(textb, wvb, BD * LD, DD, bv, vraw);
  ln_rows_k<<<(BD * LD + 3) / 4, 256, 0, stream>>>(kraw, g2, b2, kh, BD * LD);
  make_vt<<<BD * NH_, 256, 0, stream>>>(vraw, vt);

  // 2: Q projection + bias + posenc + fused LN -> bf16 (in-place over xt)
  gemm_q_ln<<<dim3(BD * HWD / 64), 256, 0, stream>>>(xt, wqb, bq, g1, b1, qbf);

  // 3: attention
  attn_k<<<dim3(HWD / 64, NH_, BD), 256, 0, stream>>>(qbf, kh, vt, attn_o);

  // 4: output projection (+bias +residual), transposed for coalesced stores
  gemm_o<<<dim3(BD * HWD / 64), 256, 0, stream>>>(wob, attn_o, bo, x, out);
}